// Round 23
// baseline (147.635 us; speedup 1.0000x reference)
//
#include <hip/hip_runtime.h>
#include <hip/hip_bf16.h>
#include <stdint.h>

#define NROWS   32768     // 32*32*32
#define DIMD    256
#define NATOMS  1024

typedef short  bf16x8 __attribute__((ext_vector_type(8)));
typedef float  f32x4  __attribute__((ext_vector_type(4)));

__device__ __forceinline__ unsigned short bf16rne(float f) {
    unsigned u = __float_as_uint(f);
    u = u + 0x7FFFu + ((u >> 16) & 1u);
    return (unsigned short)(u >> 16);
}

// ---------------------------------------------------------------------------
// B prep: planes Bs[2][8][1024][32] bf16 (m: 0=rep,1=dict; kc; atom; k-in-32)
// K-major tiling -> each MFMA atom-fragment is a contiguous 1KB global read.
// Also dict row norms (fp32), and block 0 zeroes counts (replaces memset).
__global__ __launch_bounds__(256) void vq_bprep(
    const float* __restrict__ rep_w, const float* __restrict__ dict_w,
    unsigned short* __restrict__ Bs, float* __restrict__ dnorm,
    int* __restrict__ counts)
{
    const int tid = threadIdx.x;
    if (blockIdx.x == 0) {
        for (int i = tid; i < NATOMS; i += 256) counts[i] = 0;
    }
    const int atom = blockIdx.x * 32 + (tid >> 3);   // 32 blocks
    const int kc = tid & 7;                          // k-chunk of 32
    float ss = 0.f;
#pragma unroll
    for (int m = 0; m < 2; ++m) {
        const float* src = (m ? dict_w : rep_w) + (size_t)atom * DIMD + kc * 32;
        unsigned short* dst = Bs + (size_t)m * 262144 + (size_t)kc * 32768 + atom * 32;
#pragma unroll
        for (int q = 0; q < 8; ++q) {
            float4 v = *(const float4*)&src[q * 4];
            float fv[4] = {v.x, v.y, v.z, v.w};
            unsigned short a0[4];
#pragma unroll
            for (int e = 0; e < 4; ++e) {
                if (m) ss = fmaf(fv[e], fv[e], ss);
                a0[e] = bf16rne(fv[e]);
            }
            *(ushort4*)&dst[q * 4] = make_ushort4(a0[0], a0[1], a0[2], a0[3]);
        }
    }
    ss += __shfl_down(ss, 4, 8);
    ss += __shfl_down(ss, 2, 8);
    ss += __shfl_down(ss, 1, 8);
    if (kc == 0) dnorm[atom] = ss;
}

// ---------------------------------------------------------------------------
// Branch-free insert of key u into sorted-ascending 8-list: clamp chain.
__device__ __forceinline__ void insk(unsigned u, unsigned (&kd)[8]) {
#pragma unroll
    for (int j = 7; j >= 1; --j)
        kd[j] = min(max(u, kd[j - 1]), kd[j]);
    kd[0] = min(u, kd[0]);
}

// in-wave merge of sorted key-lists over lane-groups (parts in lanes c+16k)
__device__ __forceinline__ void wave_merge_k(int lane, unsigned (&kd)[8], float& se) {
#pragma unroll
    for (int half = 32; half >= 16; half >>= 1) {
        const int src = (lane + half) & 63;
        unsigned ko[8];
#pragma unroll
        for (int j = 0; j < 8; ++j) ko[j] = (unsigned)__shfl((int)kd[j], src, 64);
        const float so = __shfl(se, src, 64);
        if (lane < half) {
            se += so;
#pragma unroll
            for (int t = 0; t < 8; ++t) insk(ko[t], kd);
        }
    }
}

// ---------------------------------------------------------------------------
// Fused main: dual GEMM (logits+dists, bf16, swapped MFMA operands, 4 A
// row-frags/wave, 64-row blocks, grid 512 = one generation) + full epilogue
// in the tail. R23 change: all 4 rf MFMA blocks run back-to-back, the B
// prefetch for it+1 issues the moment bL/bD are dead, and the 4 scans run
// AFTER the prefetch -- ~1600 VALU cycles now cover the L2 load latency
// that previously stalled each iteration start. launch_bounds(256,2)
// LOCKED (spilled 3x tighter). Tail values flow through LDS (R12/R21).
__global__ __launch_bounds__(256, 2) void vq_main(
    const float* __restrict__ z_e, const unsigned short* __restrict__ Bs,
    const float* __restrict__ rep_b, const float* __restrict__ dnorm,
    const float* __restrict__ rep_w, const float* __restrict__ dict_w,
    float* __restrict__ rep_sparse, float* __restrict__ z_st,
    float* __restrict__ partials, int* __restrict__ counts)
{
    __shared__ __align__(16) float rbS[1024];
    __shared__ __align__(16) float dnS[1024];
    __shared__ unsigned mKu[3][64][8];
    __shared__ float mS[3][64];
    __shared__ unsigned fK[64][8];
    __shared__ float fSum[64];
    __shared__ __align__(16) float zL[32][260];   // tail: z_e slab -> z_dl -> hist
    __shared__ int   iW[256];
    __shared__ float wS[256];
    __shared__ float red[256];

    const int tid = threadIdx.x;
    const int lane = tid & 63, w = tid >> 6;     // w = atom quarter
    const int c = lane & 15, lg = lane >> 4;
    const int row0 = blockIdx.x * 64;
    const int bb = row0 >> 10, hw0 = row0 & 1023;   // 64 | 1024, no straddle

    for (int i = tid; i < 1024; i += 256) { rbS[i] = rep_b[i]; dnS[i] = dnorm[i]; }

    const char* pL = (const char*)Bs;             // rep plane  [8][1024][32]
    const char* pD = (const char*)Bs + 524288;    // dict plane
    const int abase = w << 8;                     // 256 atoms per quarter

    // first B tile (atoms abase..abase+15): frag = 16 atoms x 32k, 1KB each
    bf16x8 bL[8], bD[8];
    {
        const int off = ((abase + c) << 6) + (lg << 4);
#pragma unroll
        for (int kc = 0; kc < 8; ++kc) {
            bL[kc] = *(const bf16x8*)(pL + ((size_t)kc << 16) + off);
            bD[kc] = *(const bf16x8*)(pD + ((size_t)kc << 16) + off);
        }
    }

    // A: 4 row-frags, rows rf*16 + c, k = kc*32 + lg*8 + e, bf16 1-term.
    bf16x8 A[4][8];
    {
        const float* zb = z_e + (size_t)bb * 262144 + hw0 + c;
#pragma unroll
        for (int kc = 0; kc < 8; ++kc) {
            float f[4][8];
#pragma unroll
            for (int e = 0; e < 8; ++e) {
                const float* p = zb + (size_t)(kc * 32 + lg * 8 + e) * 1024;
                f[0][e] = p[0];
                f[1][e] = p[16];
                f[2][e] = p[32];
                f[3][e] = p[48];
            }
#pragma unroll
            for (int rf = 0; rf < 4; ++rf)
#pragma unroll
                for (int e = 0; e < 8; ++e)
                    A[rf][kc][e] = (short)bf16rne(f[rf][e]);
        }
    }
    __syncthreads();   // tables staged

    // per-lane online state: frag rf = row rf*16+c (part lg, quarter w)
    unsigned kd[4][8];
    float se[4] = {0.f, 0.f, 0.f, 0.f};
#pragma unroll
    for (int rf = 0; rf < 4; ++rf)
#pragma unroll
        for (int j = 0; j < 8; ++j) kd[rf][j] = 0xFFFFFFFFu;

    for (int it = 0; it < 16; ++it) {
        const int tb = abase + (it << 4) + (lg << 2);
        const f32x4 rbv = *(const f32x4*)&rbS[tb];
        const f32x4 dnv = *(const f32x4*)&dnS[tb];

        // all 4 rf MFMA blocks back-to-back (accs statically indexed)
        f32x4 aL0 = {0.f,0.f,0.f,0.f}, aD0 = {0.f,0.f,0.f,0.f};
        f32x4 aL1 = {0.f,0.f,0.f,0.f}, aD1 = {0.f,0.f,0.f,0.f};
        f32x4 aL2 = {0.f,0.f,0.f,0.f}, aD2 = {0.f,0.f,0.f,0.f};
        f32x4 aL3 = {0.f,0.f,0.f,0.f}, aD3 = {0.f,0.f,0.f,0.f};
#pragma unroll
        for (int kc = 0; kc < 8; ++kc) {
            aL0 = __builtin_amdgcn_mfma_f32_16x16x32_bf16(bL[kc], A[0][kc], aL0, 0, 0, 0);
            aD0 = __builtin_amdgcn_mfma_f32_16x16x32_bf16(bD[kc], A[0][kc], aD0, 0, 0, 0);
            aL1 = __builtin_amdgcn_mfma_f32_16x16x32_bf16(bL[kc], A[1][kc], aL1, 0, 0, 0);
            aD1 = __builtin_amdgcn_mfma_f32_16x16x32_bf16(bD[kc], A[1][kc], aD1, 0, 0, 0);
            aL2 = __builtin_amdgcn_mfma_f32_16x16x32_bf16(bL[kc], A[2][kc], aL2, 0, 0, 0);
            aD2 = __builtin_amdgcn_mfma_f32_16x16x32_bf16(bD[kc], A[2][kc], aD2, 0, 0, 0);
            aL3 = __builtin_amdgcn_mfma_f32_16x16x32_bf16(bL[kc], A[3][kc], aL3, 0, 0, 0);
            aD3 = __builtin_amdgcn_mfma_f32_16x16x32_bf16(bD[kc], A[3][kc], aD3, 0, 0, 0);
        }

        // bL/bD dead -> issue next tile's prefetch NOW (scans cover latency)
        if (it < 15) {
            const int off = ((abase + (it + 1) * 16 + c) << 6) + (lg << 4);
#pragma unroll
            for (int kc = 0; kc < 8; ++kc) {
                bL[kc] = *(const bf16x8*)(pL + ((size_t)kc << 16) + off);
                bD[kc] = *(const bf16x8*)(pD + ((size_t)kc << 16) + off);
            }
        }

        // scans for all 4 rf (pure VALU; overlaps the in-flight prefetch)
#pragma unroll
        for (int q = 0; q < 4; ++q) {
            const unsigned atom = (unsigned)(tb + q);
            const float rb = rbv[q], dn = dnv[q];
            se[0] += __expf(aL0[q] + rb);
            se[1] += __expf(aL1[q] + rb);
            se[2] += __expf(aL2[q] + rb);
            se[3] += __expf(aL3[q] + rb);
            unsigned u0 = __float_as_uint(dn - 2.0f * aD0[q]);
            u0 ^= ((unsigned)((int)u0 >> 31) | 0x80000000u);
            insk((u0 & ~1023u) | atom, kd[0]);
            unsigned u1 = __float_as_uint(dn - 2.0f * aD1[q]);
            u1 ^= ((unsigned)((int)u1 >> 31) | 0x80000000u);
            insk((u1 & ~1023u) | atom, kd[1]);
            unsigned u2 = __float_as_uint(dn - 2.0f * aD2[q]);
            u2 ^= ((unsigned)((int)u2 >> 31) | 0x80000000u);
            insk((u2 & ~1023u) | atom, kd[2]);
            unsigned u3 = __float_as_uint(dn - 2.0f * aD3[q]);
            u3 ^= ((unsigned)((int)u3 >> 31) | 0x80000000u);
            insk((u3 & ~1023u) | atom, kd[3]);
        }
    }

    // ---- in-wave merges (parts lg -> lanes 0..15), all 4 frags
#pragma unroll
    for (int rf = 0; rf < 4; ++rf)
        wave_merge_k(lane, kd[rf], se[rf]);

    // quarters 1..3 publish to LDS
    if (w >= 1 && lane < 16) {
#pragma unroll
        for (int rf = 0; rf < 4; ++rf) {
#pragma unroll
            for (int j = 0; j < 8; ++j)
                mKu[w - 1][rf * 16 + c][j] = kd[rf][j];
            mS[w - 1][rf * 16 + c] = se[rf];
        }
    }
    __syncthreads();

    // quarter-0 wave: merge other quarters, publish final keys + sums
    if (w == 0 && lane < 16) {
#pragma unroll
        for (int rf = 0; rf < 4; ++rf) {
            const int rloc = rf * 16 + c;
            for (int p = 0; p < 3; ++p)
#pragma unroll
                for (int t = 0; t < 8; ++t)
                    insk(mKu[p][rloc][t], kd[rf]);
            se[rf] += mS[0][rloc] + mS[1][rloc] + mS[2][rloc];
#pragma unroll
            for (int j = 0; j < 8; ++j) fK[rloc][j] = kd[rf][j];
            fSum[rloc] = se[rf];
        }
    }
    __syncthreads();   // fK/fSum final

    // ================= fused epilogue: two 32-row halves =================
    const int m31 = tid & 31, dg = tid >> 5;   // staging decomposition
    const int j8 = tid >> 5, rr = tid & 31;    // (slot, row) decomposition
    float lossacc = 0.f;

    for (int h = 0; h < 2; ++h) {
        const int r0 = h * 32;   // local row base within block

        // zero-fill this half's rep_sparse rows (fire-and-forget)
        {
            float4 z4 = {0.f, 0.f, 0.f, 0.f};
            float4* rp4 = (float4*)rep_sparse
                        + (size_t)(row0 + r0) * (NATOMS / 4) + tid;
            for (int r = 0; r < 32; ++r)
                rp4[(size_t)r * (NATOMS / 4)] = z4;
        }

        // stage z_e slab (coalesced NCHW re-read)
        {
            const float* zb2 = z_e + (size_t)bb * 262144 + hw0 + r0 + m31;
            for (int it = 0; it < 32; ++it) {
                const int d = it * 8 + dg;
                zL[m31][d] = zb2[(size_t)d * 1024];
            }
        }
        __syncthreads();   // slab staged (also previous-half zL reads done)

        // fp32 logits for the 8 winners; thread = (slot j8, row rr)
        {
            const int idx = (int)(fK[r0 + rr][j8] & 1023u);
            const float* rw = rep_w + (size_t)idx * DIMD;
            float acc = 0.f;
            for (int k = 0; k < DIMD; k += 4) {
                const float4 rv = *(const float4*)&rw[k];
                const f32x4 zv = *(const f32x4*)&zL[rr][k];
                acc = fmaf(zv[0], rv.x, acc);
                acc = fmaf(zv[1], rv.y, acc);
                acc = fmaf(zv[2], rv.z, acc);
                acc = fmaf(zv[3], rv.w, acc);
            }
            iW[rr * 8 + j8] = idx;
            wS[rr * 8 + j8] = __expf(acc + rbS[idx]) * 0.125f / fSum[r0 + rr];
        }
        __syncthreads();   // iW/wS visible; zero-fill stores drained

        // scatter weights
        rep_sparse[(size_t)(row0 + r0 + rr) * NATOMS + iW[rr * 8 + j8]]
            = wS[rr * 8 + j8];

        // z_dl in-place over the slab; loss partials. thread = d
        for (int r = 0; r < 32; ++r) {
            float acc = 0.f;
#pragma unroll
            for (int j = 0; j < 8; ++j)
                acc = fmaf(wS[r * 8 + j],
                           dict_w[(size_t)iW[r * 8 + j] * DIMD + tid], acc);
            const float diff = acc - zL[r][tid];
            lossacc = fmaf(diff, diff, lossacc);
            zL[r][tid] = acc;      // z_st value (straight-through == z_dl)
        }
        __syncthreads();

        // coalesced NCHW store of z_st from the slab
        {
            float* ob = z_st + (size_t)bb * 262144 + hw0 + r0 + m31;
            for (int it = 0; it < 32; ++it) {
                const int d = it * 8 + dg;
                ob[(size_t)d * 1024] = zL[m31][d];
            }
        }
        __syncthreads();   // zL free for next half / hist
    }

    // loss reduction
    red[tid] = lossacc;
    __syncthreads();
    for (int s = 128; s > 0; s >>= 1) {
        if (tid < s) red[tid] += red[tid + s];
        __syncthreads();
    }
    if (tid == 0) partials[blockIdx.x] = red[0];

    // histogram of this block's 512 selected indices (zL slab reused)
    __syncthreads();
    int* hS = (int*)zL;
    for (int i = tid; i < 1024; i += 256) hS[i] = 0;
    __syncthreads();
    atomicAdd(&hS[(int)(fK[tid >> 3][tid & 7] & 1023u)], 1);
    atomicAdd(&hS[(int)(fK[32 + (tid >> 3)][tid & 7] & 1023u)], 1);
    __syncthreads();
    for (int i = tid; i < 1024; i += 256)
        if (hS[i]) atomicAdd(&counts[i], hS[i]);
}

// ---------------------------------------------------------------------------
// Finalize: loss and perplexity (deterministic fixed-order reductions)
__global__ void vq_final(const float* __restrict__ partials,
                         const int* __restrict__ counts,
                         float* __restrict__ out_loss, float* __restrict__ out_perp)
{
    __shared__ double dred[256];
    __shared__ float fred[256];
    const int tid = threadIdx.x;
    double s = 0.0;
    for (int i = tid; i < 512; i += 256) s += (double)partials[i];
    dred[tid] = s;
    __syncthreads();
    for (int st = 128; st > 0; st >>= 1) {
        if (tid < st) dred[tid] += dred[tid + st];
        __syncthreads();
    }
    float ps = 0.f;
    for (int i = tid; i < NATOMS; i += 256) {
        const float p = (float)counts[i] * (1.0f / 262144.0f);
        ps += p * logf(p + 1e-10f);
    }
    fred[tid] = ps;
    __syncthreads();
    for (int st = 128; st > 0; st >>= 1) {
        if (tid < st) fred[tid] += fred[tid + st];
        __syncthreads();
    }
    if (tid == 0) {
        *out_loss = 0.25f * (float)(dred[0] / 8388608.0);
        *out_perp = expf(-fred[0]);
    }
}

// ---------------------------------------------------------------------------
extern "C" void kernel_launch(void* const* d_in, const int* in_sizes, int n_in,
                              void* d_out, int out_size, void* d_ws, size_t ws_size,
                              hipStream_t stream) {
    const float* z_e    = (const float*)d_in[0];
    const float* dict_w = (const float*)d_in[1];
    const float* rep_w  = (const float*)d_in[2];
    const float* rep_b  = (const float*)d_in[3];

    float* out = (float*)d_out;
    float* out_loss   = out;                      // [0]
    float* z_st       = out + 1;                  // [1 .. 8388608]
    float* out_perp   = out + 1 + 8388608;        // [8388609]
    float* rep_sparse = out + 2 + 8388608;        // [8388610 ..] 32768x1024

    // Bs parked in WS scratch (z_st region would race with fused tail).
    char* ws = (char*)d_ws;
    unsigned short* Bs = (unsigned short*)(ws + (1 << 20));       // 1 MB @ 1MB
    int*   counts   = (int*)(ws);                                 // 4 KB
    float* dnorm    = (float*)(ws + 4096);                        // 4 KB
    float* partials = (float*)(ws + 8192);                        // 2 KB

    vq_bprep<<<32, 256, 0, stream>>>(rep_w, dict_w, Bs, dnorm, counts);
    vq_main<<<NROWS / 64, 256, 0, stream>>>(z_e, Bs, rep_b, dnorm,
                                            rep_w, dict_w,
                                            rep_sparse, z_st, partials, counts);
    vq_final<<<1, 256, 0, stream>>>(partials, counts, out_loss, out_perp);
}

// Round 24
// 142.437 us; speedup vs baseline: 1.0365x; 1.0365x over previous
//
#include <hip/hip_runtime.h>
#include <hip/hip_bf16.h>
#include <stdint.h>

#define NROWS   32768     // 32*32*32
#define DIMD    256
#define NATOMS  1024

typedef short  bf16x8 __attribute__((ext_vector_type(8)));
typedef float  f32x4  __attribute__((ext_vector_type(4)));

__device__ __forceinline__ unsigned short bf16rne(float f) {
    unsigned u = __float_as_uint(f);
    u = u + 0x7FFFu + ((u >> 16) & 1u);
    return (unsigned short)(u >> 16);
}

// ---------------------------------------------------------------------------
// B prep: planes Bs[2][8][1024][32] bf16 (m: 0=rep,1=dict; kc; atom; k-in-32)
// K-major tiling -> each MFMA atom-fragment is a contiguous 1KB global read.
// Also dict row norms (fp32), and block 0 zeroes counts (replaces memset).
__global__ __launch_bounds__(256) void vq_bprep(
    const float* __restrict__ rep_w, const float* __restrict__ dict_w,
    unsigned short* __restrict__ Bs, float* __restrict__ dnorm,
    int* __restrict__ counts)
{
    const int tid = threadIdx.x;
    if (blockIdx.x == 0) {
        for (int i = tid; i < NATOMS; i += 256) counts[i] = 0;
    }
    const int atom = blockIdx.x * 32 + (tid >> 3);   // 32 blocks
    const int kc = tid & 7;                          // k-chunk of 32
    float ss = 0.f;
#pragma unroll
    for (int m = 0; m < 2; ++m) {
        const float* src = (m ? dict_w : rep_w) + (size_t)atom * DIMD + kc * 32;
        unsigned short* dst = Bs + (size_t)m * 262144 + (size_t)kc * 32768 + atom * 32;
#pragma unroll
        for (int q = 0; q < 8; ++q) {
            float4 v = *(const float4*)&src[q * 4];
            float fv[4] = {v.x, v.y, v.z, v.w};
            unsigned short a0[4];
#pragma unroll
            for (int e = 0; e < 4; ++e) {
                if (m) ss = fmaf(fv[e], fv[e], ss);
                a0[e] = bf16rne(fv[e]);
            }
            *(ushort4*)&dst[q * 4] = make_ushort4(a0[0], a0[1], a0[2], a0[3]);
        }
    }
    ss += __shfl_down(ss, 4, 8);
    ss += __shfl_down(ss, 2, 8);
    ss += __shfl_down(ss, 1, 8);
    if (kc == 0) dnorm[atom] = ss;
}

// ---------------------------------------------------------------------------
// Branch-free insert of key u into sorted-ascending 8-list: clamp chain.
__device__ __forceinline__ void insk(unsigned u, unsigned (&kd)[8]) {
#pragma unroll
    for (int j = 7; j >= 1; --j)
        kd[j] = min(max(u, kd[j - 1]), kd[j]);
    kd[0] = min(u, kd[0]);
}

// in-wave merge of sorted key-lists over lane-groups (parts in lanes c+16k)
__device__ __forceinline__ void wave_merge_k(int lane, unsigned (&kd)[8], float& se) {
#pragma unroll
    for (int half = 32; half >= 16; half >>= 1) {
        const int src = (lane + half) & 63;
        unsigned ko[8];
#pragma unroll
        for (int j = 0; j < 8; ++j) ko[j] = (unsigned)__shfl((int)kd[j], src, 64);
        const float so = __shfl(se, src, 64);
        if (lane < half) {
            se += so;
#pragma unroll
            for (int t = 0; t < 8; ++t) insk(ko[t], kd);
        }
    }
}

// ---------------------------------------------------------------------------
// Fused main: dual GEMM (logits+dists, bf16, swapped MFMA operands, 4 A
// row-frags/wave, 64-row blocks, grid 512 = one generation) + full epilogue
// in the tail (fp32 logit recovery, softmax weights, rep_sparse fill+scatter,
// z_dl, loss partials, z_st, histogram). Tail processes 64 rows as two
// 32-row halves through a 33 KB fp32 LDS slab -- finished blocks' HBM work
// overlaps still-running blocks' compute. launch_bounds(256,2) LOCKED
// (spilled 3x tighter: R10/R14/R17). Tail values flow through LDS, never
// held in registers across phases (R12/R21 spill lessons). Per-rf
// sequential MFMA+scan (R23's hoist was neutral -- compiler already
// schedules the prefetch early).
__global__ __launch_bounds__(256, 2) void vq_main(
    const float* __restrict__ z_e, const unsigned short* __restrict__ Bs,
    const float* __restrict__ rep_b, const float* __restrict__ dnorm,
    const float* __restrict__ rep_w, const float* __restrict__ dict_w,
    float* __restrict__ rep_sparse, float* __restrict__ z_st,
    float* __restrict__ partials, int* __restrict__ counts)
{
    __shared__ __align__(16) float rbS[1024];
    __shared__ __align__(16) float dnS[1024];
    __shared__ unsigned mKu[3][64][8];
    __shared__ float mS[3][64];
    __shared__ unsigned fK[64][8];
    __shared__ float fSum[64];
    __shared__ __align__(16) float zL[32][260];   // tail: z_e slab -> z_dl -> hist
    __shared__ int   iW[256];
    __shared__ float wS[256];
    __shared__ float red[256];

    const int tid = threadIdx.x;
    const int lane = tid & 63, w = tid >> 6;     // w = atom quarter
    const int c = lane & 15, lg = lane >> 4;
    const int row0 = blockIdx.x * 64;
    const int bb = row0 >> 10, hw0 = row0 & 1023;   // 64 | 1024, no straddle

    for (int i = tid; i < 1024; i += 256) { rbS[i] = rep_b[i]; dnS[i] = dnorm[i]; }

    const char* pL = (const char*)Bs;             // rep plane  [8][1024][32]
    const char* pD = (const char*)Bs + 524288;    // dict plane
    const int abase = w << 8;                     // 256 atoms per quarter

    // first B tile (atoms abase..abase+15): frag = 16 atoms x 32k, 1KB each
    bf16x8 bL[8], bD[8];
    {
        const int off = ((abase + c) << 6) + (lg << 4);
#pragma unroll
        for (int kc = 0; kc < 8; ++kc) {
            bL[kc] = *(const bf16x8*)(pL + ((size_t)kc << 16) + off);
            bD[kc] = *(const bf16x8*)(pD + ((size_t)kc << 16) + off);
        }
    }

    // A: 4 row-frags, rows rf*16 + c, k = kc*32 + lg*8 + e, bf16 1-term.
    bf16x8 A[4][8];
    {
        const float* zb = z_e + (size_t)bb * 262144 + hw0 + c;
#pragma unroll
        for (int kc = 0; kc < 8; ++kc) {
            float f[4][8];
#pragma unroll
            for (int e = 0; e < 8; ++e) {
                const float* p = zb + (size_t)(kc * 32 + lg * 8 + e) * 1024;
                f[0][e] = p[0];
                f[1][e] = p[16];
                f[2][e] = p[32];
                f[3][e] = p[48];
            }
#pragma unroll
            for (int rf = 0; rf < 4; ++rf)
#pragma unroll
                for (int e = 0; e < 8; ++e)
                    A[rf][kc][e] = (short)bf16rne(f[rf][e]);
        }
    }
    __syncthreads();   // tables staged

    // per-lane online state: frag rf = row rf*16+c (part lg, quarter w)
    unsigned kd[4][8];
    float se[4] = {0.f, 0.f, 0.f, 0.f};
#pragma unroll
    for (int rf = 0; rf < 4; ++rf)
#pragma unroll
        for (int j = 0; j < 8; ++j) kd[rf][j] = 0xFFFFFFFFu;

    for (int it = 0; it < 16; ++it) {
        const int tb = abase + (it << 4) + (lg << 2);
        const f32x4 rbv = *(const f32x4*)&rbS[tb];
        const f32x4 dnv = *(const f32x4*)&dnS[tb];

        // per-rf: MFMA pair then scan (keeps only 8 acc regs live at a time)
#pragma unroll
        for (int rf = 0; rf < 4; ++rf) {
            f32x4 aL = {0.f, 0.f, 0.f, 0.f};
            f32x4 aD = {0.f, 0.f, 0.f, 0.f};
#pragma unroll
            for (int kc = 0; kc < 8; ++kc) {
                aL = __builtin_amdgcn_mfma_f32_16x16x32_bf16(bL[kc], A[rf][kc], aL, 0, 0, 0);
                aD = __builtin_amdgcn_mfma_f32_16x16x32_bf16(bD[kc], A[rf][kc], aD, 0, 0, 0);
            }
#pragma unroll
            for (int q = 0; q < 4; ++q) {
                const unsigned atom = (unsigned)(tb + q);
                se[rf] += __expf(aL[q] + rbv[q]);
                unsigned u = __float_as_uint(dnv[q] - 2.0f * aD[q]);
                u ^= ((unsigned)((int)u >> 31) | 0x80000000u);
                insk((u & ~1023u) | atom, kd[rf]);
            }
        }

        // prefetch next B tile (bL/bD dead after rf=3's MFMA block)
        if (it < 15) {
            const int off = ((abase + (it + 1) * 16 + c) << 6) + (lg << 4);
#pragma unroll
            for (int kc = 0; kc < 8; ++kc) {
                bL[kc] = *(const bf16x8*)(pL + ((size_t)kc << 16) + off);
                bD[kc] = *(const bf16x8*)(pD + ((size_t)kc << 16) + off);
            }
        }
    }

    // ---- in-wave merges (parts lg -> lanes 0..15), all 4 frags
#pragma unroll
    for (int rf = 0; rf < 4; ++rf)
        wave_merge_k(lane, kd[rf], se[rf]);

    // quarters 1..3 publish to LDS
    if (w >= 1 && lane < 16) {
#pragma unroll
        for (int rf = 0; rf < 4; ++rf) {
#pragma unroll
            for (int j = 0; j < 8; ++j)
                mKu[w - 1][rf * 16 + c][j] = kd[rf][j];
            mS[w - 1][rf * 16 + c] = se[rf];
        }
    }
    __syncthreads();

    // quarter-0 wave: merge other quarters, publish final keys + sums
    if (w == 0 && lane < 16) {
#pragma unroll
        for (int rf = 0; rf < 4; ++rf) {
            const int rloc = rf * 16 + c;
            for (int p = 0; p < 3; ++p)
#pragma unroll
                for (int t = 0; t < 8; ++t)
                    insk(mKu[p][rloc][t], kd[rf]);
            se[rf] += mS[0][rloc] + mS[1][rloc] + mS[2][rloc];
#pragma unroll
            for (int j = 0; j < 8; ++j) fK[rloc][j] = kd[rf][j];
            fSum[rloc] = se[rf];
        }
    }
    __syncthreads();   // fK/fSum final

    // ================= fused epilogue: two 32-row halves =================
    const int m31 = tid & 31, dg = tid >> 5;   // staging decomposition
    const int j8 = tid >> 5, rr = tid & 31;    // (slot, row) decomposition
    float lossacc = 0.f;

    for (int h = 0; h < 2; ++h) {
        const int r0 = h * 32;   // local row base within block

        // zero-fill this half's rep_sparse rows (fire-and-forget)
        {
            float4 z4 = {0.f, 0.f, 0.f, 0.f};
            float4* rp4 = (float4*)rep_sparse
                        + (size_t)(row0 + r0) * (NATOMS / 4) + tid;
            for (int r = 0; r < 32; ++r)
                rp4[(size_t)r * (NATOMS / 4)] = z4;
        }

        // stage z_e slab (coalesced NCHW re-read)
        {
            const float* zb2 = z_e + (size_t)bb * 262144 + hw0 + r0 + m31;
            for (int it = 0; it < 32; ++it) {
                const int d = it * 8 + dg;
                zL[m31][d] = zb2[(size_t)d * 1024];
            }
        }
        __syncthreads();   // slab staged (also previous-half zL reads done)

        // fp32 logits for the 8 winners; thread = (slot j8, row rr)
        {
            const int idx = (int)(fK[r0 + rr][j8] & 1023u);
            const float* rw = rep_w + (size_t)idx * DIMD;
            float acc = 0.f;
            for (int k = 0; k < DIMD; k += 4) {
                const float4 rv = *(const float4*)&rw[k];
                const f32x4 zv = *(const f32x4*)&zL[rr][k];
                acc = fmaf(zv[0], rv.x, acc);
                acc = fmaf(zv[1], rv.y, acc);
                acc = fmaf(zv[2], rv.z, acc);
                acc = fmaf(zv[3], rv.w, acc);
            }
            iW[rr * 8 + j8] = idx;
            wS[rr * 8 + j8] = __expf(acc + rbS[idx]) * 0.125f / fSum[r0 + rr];
        }
        __syncthreads();   // iW/wS visible; zero-fill stores drained

        // scatter weights
        rep_sparse[(size_t)(row0 + r0 + rr) * NATOMS + iW[rr * 8 + j8]]
            = wS[rr * 8 + j8];

        // z_dl in-place over the slab; loss partials. thread = d
        for (int r = 0; r < 32; ++r) {
            float acc = 0.f;
#pragma unroll
            for (int j = 0; j < 8; ++j)
                acc = fmaf(wS[r * 8 + j],
                           dict_w[(size_t)iW[r * 8 + j] * DIMD + tid], acc);
            const float diff = acc - zL[r][tid];
            lossacc = fmaf(diff, diff, lossacc);
            zL[r][tid] = acc;      // z_st value (straight-through == z_dl)
        }
        __syncthreads();

        // coalesced NCHW store of z_st from the slab
        {
            float* ob = z_st + (size_t)bb * 262144 + hw0 + r0 + m31;
            for (int it = 0; it < 32; ++it) {
                const int d = it * 8 + dg;
                ob[(size_t)d * 1024] = zL[m31][d];
            }
        }
        __syncthreads();   // zL free for next half / hist
    }

    // loss reduction
    red[tid] = lossacc;
    __syncthreads();
    for (int s = 128; s > 0; s >>= 1) {
        if (tid < s) red[tid] += red[tid + s];
        __syncthreads();
    }
    if (tid == 0) partials[blockIdx.x] = red[0];

    // histogram of this block's 512 selected indices (zL slab reused)
    __syncthreads();
    int* hS = (int*)zL;
    for (int i = tid; i < 1024; i += 256) hS[i] = 0;
    __syncthreads();
    atomicAdd(&hS[(int)(fK[tid >> 3][tid & 7] & 1023u)], 1);
    atomicAdd(&hS[(int)(fK[32 + (tid >> 3)][tid & 7] & 1023u)], 1);
    __syncthreads();
    for (int i = tid; i < 1024; i += 256)
        if (hS[i]) atomicAdd(&counts[i], hS[i]);
}

// ---------------------------------------------------------------------------
// Finalize: loss and perplexity (deterministic fixed-order reductions)
__global__ void vq_final(const float* __restrict__ partials,
                         const int* __restrict__ counts,
                         float* __restrict__ out_loss, float* __restrict__ out_perp)
{
    __shared__ double dred[256];
    __shared__ float fred[256];
    const int tid = threadIdx.x;
    double s = 0.0;
    for (int i = tid; i < 512; i += 256) s += (double)partials[i];
    dred[tid] = s;
    __syncthreads();
    for (int st = 128; st > 0; st >>= 1) {
        if (tid < st) dred[tid] += dred[tid + st];
        __syncthreads();
    }
    float ps = 0.f;
    for (int i = tid; i < NATOMS; i += 256) {
        const float p = (float)counts[i] * (1.0f / 262144.0f);
        ps += p * logf(p + 1e-10f);
    }
    fred[tid] = ps;
    __syncthreads();
    for (int st = 128; st > 0; st >>= 1) {
        if (tid < st) fred[tid] += fred[tid + st];
        __syncthreads();
    }
    if (tid == 0) {
        *out_loss = 0.25f * (float)(dred[0] / 8388608.0);
        *out_perp = expf(-fred[0]);
    }
}

// ---------------------------------------------------------------------------
extern "C" void kernel_launch(void* const* d_in, const int* in_sizes, int n_in,
                              void* d_out, int out_size, void* d_ws, size_t ws_size,
                              hipStream_t stream) {
    const float* z_e    = (const float*)d_in[0];
    const float* dict_w = (const float*)d_in[1];
    const float* rep_w  = (const float*)d_in[2];
    const float* rep_b  = (const float*)d_in[3];

    float* out = (float*)d_out;
    float* out_loss   = out;                      // [0]
    float* z_st       = out + 1;                  // [1 .. 8388608]
    float* out_perp   = out + 1 + 8388608;        // [8388609]
    float* rep_sparse = out + 2 + 8388608;        // [8388610 ..] 32768x1024

    // Bs parked in WS scratch (z_st region would race with fused tail).
    char* ws = (char*)d_ws;
    unsigned short* Bs = (unsigned short*)(ws + (1 << 20));       // 1 MB @ 1MB
    int*   counts   = (int*)(ws);                                 // 4 KB
    float* dnorm    = (float*)(ws + 4096);                        // 4 KB
    float* partials = (float*)(ws + 8192);                        // 2 KB

    vq_bprep<<<32, 256, 0, stream>>>(rep_w, dict_w, Bs, dnorm, counts);
    vq_main<<<NROWS / 64, 256, 0, stream>>>(z_e, Bs, rep_b, dnorm,
                                            rep_w, dict_w,
                                            rep_sparse, z_st, partials, counts);
    vq_final<<<1, 256, 0, stream>>>(partials, counts, out_loss, out_perp);
}